// Round 6
// baseline (1100.966 us; speedup 1.0000x reference)
//
#include <hip/hip_runtime.h>

// Phi3 quantized MLP on MI355X (gfx950) — R11: R9 math + occupancy bump.
// R10 post-mortem (FAIL 28.0 > 18.72): act double-round + weight-flat each add ~4-6
// absmax vs R9's 17.0 with 1.7 headroom -> full-flat GEMM2 is dead at int8. Revert
// GEMM2 to R9's exact per-group rescale (bit-identical, absmax 17.0).
// Budget recount: 743 = gateup 233 + preproc ~90 + gemm_down ~350-390 (!). down has
// HALF gateup's MFMA work but: 768 blocks @ 2 blk/CU = 1.5 rounds (round 2 at 50%
// util) and only 1 other block to hide the per-K-step barrier drain. Its LDS is
// 33 KB -> 4 blocks/CU fit (132<=160 KB), VGPR 116<=128: all 768 blocks co-resident,
// 4x drain-overlap pool. gateup: 50.7 KB -> 3 blocks/CU (152<=160), VGPR<=170.
// Only change vs R9: __launch_bounds__ min-waves targets (down 2->4, gateup 2->3).

typedef float f32x4 __attribute__((ext_vector_type(4)));
typedef float f32x2 __attribute__((ext_vector_type(2)));
typedef int   i32x4 __attribute__((ext_vector_type(4)));

__device__ __forceinline__ void gload16(const void* g, void* l) {
  __builtin_amdgcn_global_load_lds(
      (const __attribute__((address_space(1))) void*)g,
      (__attribute__((address_space(3))) void*)l, 16, 0, 0);
}

// ---------------- quantize x: f32 -> int8, ONE scale per row-quad (4 rows x full K) ----------------
__global__ __launch_bounds__(256) void quant_x_flat(const float* __restrict__ x,
                                                    signed char* __restrict__ Xq,
                                                    float* __restrict__ Xs) {
  int rq   = blockIdx.x;
  int w    = threadIdx.x >> 6;
  int lane = threadIdx.x & 63;
  size_t rowbase = ((size_t)rq * 4 + w) * 3072;
  __shared__ float wmax[4];
  float4 v[12];
  float m = 0.f;
#pragma unroll
  for (int it = 0; it < 12; ++it) {
    v[it] = *(const float4*)(x + rowbase + (lane + it * 64) * 4);
    m = fmaxf(m, fmaxf(fmaxf(fabsf(v[it].x), fabsf(v[it].y)),
                       fmaxf(fabsf(v[it].z), fabsf(v[it].w))));
  }
#pragma unroll
  for (int s = 1; s < 64; s <<= 1) m = fmaxf(m, __shfl_xor(m, s));
  if (lane == 0) wmax[w] = m;
  __syncthreads();
  float m4 = fmaxf(fmaxf(wmax[0], wmax[1]), fmaxf(wmax[2], wmax[3]));
  float inv = m4 > 0.f ? 127.f / m4 : 0.f;
#pragma unroll
  for (int it = 0; it < 12; ++it) {
    int a = (int)rintf(v[it].x * inv);
    int b = (int)rintf(v[it].y * inv);
    int c = (int)rintf(v[it].z * inv);
    int d = (int)rintf(v[it].w * inv);
    int pk = (a & 0xff) | ((b & 0xff) << 8) | ((c & 0xff) << 16) | ((d & 0xff) << 24);
    *(int*)(Xq + rowbase + (lane + it * 64) * 4) = pk;
  }
  if (threadIdx.x == 0) Xs[rq] = m4 * (1.f / 127.f);
}

// ---------------- requant gate/up weights: per-ROW flat int8 + row scale ----------------
__global__ __launch_bounds__(256) void requant_gup_flat(const int* __restrict__ qw,
                                                        const int* __restrict__ qz,
                                                        const float* __restrict__ sc,
                                                        signed char* __restrict__ W,
                                                        float* __restrict__ Ws) {
  int w    = threadIdx.x >> 6;
  int lane = threadIdx.x & 63;
  int r    = blockIdx.x * 4 + w;
  float smax = (lane < 24) ? sc[r * 24 + lane] : 0.f;
#pragma unroll
  for (int s = 1; s < 64; s <<= 1) smax = fmaxf(smax, __shfl_xor(smax, s));
  float rs    = smax * (15.f / 127.f);
  float invrs = 127.f / (15.f * smax);
#pragma unroll
  for (int it = 0; it < 12; ++it) {
    int cidx = lane + it * 64;
    int g    = cidx >> 5;
    int z    = qz[r * 24 + g];
    float f  = sc[r * 24 + g] * invrs;
    int4 q   = *(const int4*)(qw + (size_t)r * 3072 + cidx * 4);
    int a = (int)rintf((float)(q.x - z) * f);
    int b = (int)rintf((float)(q.y - z) * f);
    int c = (int)rintf((float)(q.z - z) * f);
    int d = (int)rintf((float)(q.w - z) * f);
    int pk = (a & 0xff) | ((b & 0xff) << 8) | ((c & 0xff) << 16) | ((d & 0xff) << 24);
    *(int*)(W + (size_t)r * 3072 + cidx * 4) = pk;
  }
  if (lane == 0) Ws[r] = rs;
}

// ---------------- requant down weights: int32 q,z -> int8 (q - z), exact ----------------
template <int K>
__global__ __launch_bounds__(256) void requant_k(const int* __restrict__ qw,
                                                 const int* __restrict__ qz,
                                                 signed char* __restrict__ W) {
  constexpr int KG = K / 128;
  constexpr int perrow = K / 8;
  int idx = blockIdx.x * 256 + threadIdx.x;
  int row = idx / perrow;
  int c8  = idx - row * perrow;
  int k   = c8 << 3;
  int z   = qz[row * KG + (k >> 7)];
  const int4* q4 = (const int4*)(qw + (size_t)row * K + k);
  int4 qa = q4[0];
  int4 qb = q4[1];
  int b0 = ((qa.x - z) & 0xff) | (((qa.y - z) & 0xff) << 8) |
           (((qa.z - z) & 0xff) << 16) | (((qa.w - z) & 0xff) << 24);
  int b1 = ((qb.x - z) & 0xff) | (((qb.y - z) & 0xff) << 8) |
           (((qb.z - z) & 0xff) << 16) | (((qb.w - z) & 0xff) << 24);
  int2 o; o.x = b0; o.y = b1;
  *(int2*)(W + (size_t)row * K + k) = o;
}

// ---------------- scale transpose: [R][G] -> [G][R] ----------------
__global__ __launch_bounds__(256) void transpose_sc(const float* __restrict__ in,
                                                    float* __restrict__ out,
                                                    int R, int G) {
  int idx = blockIdx.x * 256 + threadIdx.x;
  int r = idx / G;
  int g = idx - r * G;
  out[(size_t)g * R + r] = in[idx];
}

// LDS tile: 128 rows x 128 bytes, XOR-swizzled (phys chunk p holds logical p^(row&7)).

// ---------------- GEMM1: act = silu(x@Wg^T)*(x@Wu^T), flat int8, pure int32 K-loop ----------------
__global__ __launch_bounds__(256, 3) void gemm_gateup_i8(
    const signed char* __restrict__ Xq, const signed char* __restrict__ Wq,
    const float* __restrict__ Xs,    // [1024] per-row-quad x scale
    const float* __restrict__ WsG,   // [16384] per-row weight scale (gate then up)
    signed char* __restrict__ act,   // [4096][8192]
    float* __restrict__ As4) {       // [64][1024]
  const int K = 3072;
  const int bid = blockIdx.x;
  const int xcd = bid & 7;
  const int jb  = bid >> 3;
  const int n0  = ((xcd << 3) + (jb & 7)) * 128;
  const int m0  = (jb >> 3) * 128;
  __shared__ signed char lA[16384];
  __shared__ signed char lG[16384];
  __shared__ signed char lU[16384];
  __shared__ float rmax[2][128];
  __shared__ float rmax4[32];

  const int tid  = threadIdx.x;
  const int l    = tid & 63;
  const int quad = l >> 4;
  const int l16  = l & 15;
  const int wcI  = (tid >> 6) & 1;
  const int wr   = ((tid >> 6) >> 1) * 64;
  const int wc   = wcI * 64;

  i32x4 accg[4][4] = {};
  i32x4 accu[4][4] = {};

  int off[4];
#pragma unroll
  for (int jj = 0; jj < 4; ++jj) {
    int c   = tid + 256 * jj;
    int row = c >> 3;
    int log = (c & 7) ^ (row & 7);
    off[jj] = row * K + log * 16;
  }
  const signed char* baseA = Xq + (size_t)m0 * K;
  const signed char* baseG = Wq + (size_t)n0 * K;
  const signed char* baseU = Wq + (size_t)(8192 + n0) * K;

  int aoff[2][4], boff[2][4];
#pragma unroll
  for (int h = 0; h < 2; ++h) {
    int slot = h * 4 + quad;
#pragma unroll
    for (int i = 0; i < 4; ++i) {
      int ra = wr + i * 16 + l16;
      aoff[h][i] = ra * 128 + ((slot ^ (ra & 7)) * 16);
      int rb = wc + i * 16 + l16;
      boff[h][i] = rb * 128 + ((slot ^ (rb & 7)) * 16);
    }
  }
  const int qbase = (m0 >> 2) + (wr >> 2) + quad;

  for (int g = 0; g < 24; ++g) {
    const int kk = g << 7;
#pragma unroll
    for (int jj = 0; jj < 4; ++jj) {
      gload16(baseA + off[jj] + kk, lA + (tid + 256 * jj) * 16);
      gload16(baseG + off[jj] + kk, lG + (tid + 256 * jj) * 16);
      gload16(baseU + off[jj] + kk, lU + (tid + 256 * jj) * 16);
    }
    __syncthreads();

    i32x4 a[4][2];
#pragma unroll
    for (int i = 0; i < 4; ++i) {
      a[i][0] = *(const i32x4*)(lA + aoff[0][i]);
      a[i][1] = *(const i32x4*)(lA + aoff[1][i]);
    }
    __builtin_amdgcn_s_setprio(1);
#pragma unroll
    for (int jj = 0; jj < 4; ++jj) {
      i32x4 bg0 = *(const i32x4*)(lG + boff[0][jj]);
      i32x4 bg1 = *(const i32x4*)(lG + boff[1][jj]);
      i32x4 bu0 = *(const i32x4*)(lU + boff[0][jj]);
      i32x4 bu1 = *(const i32x4*)(lU + boff[1][jj]);
#pragma unroll
      for (int i = 0; i < 4; ++i) {
        accg[i][jj] = __builtin_amdgcn_mfma_i32_16x16x64_i8(a[i][0], bg0, accg[i][jj], 0, 0, 0);
        accg[i][jj] = __builtin_amdgcn_mfma_i32_16x16x64_i8(a[i][1], bg1, accg[i][jj], 0, 0, 0);
        accu[i][jj] = __builtin_amdgcn_mfma_i32_16x16x64_i8(a[i][0], bu0, accu[i][jj], 0, 0, 0);
        accu[i][jj] = __builtin_amdgcn_mfma_i32_16x16x64_i8(a[i][1], bu1, accu[i][jj], 0, 0, 0);
      }
    }
    __builtin_amdgcn_s_setprio(0);
    __syncthreads();
  }

  // ---- epilogue: dequant (flat scales) -> silu(g)*u -> quad-shared absmax -> int8 ----
  float sxf[4], wsg[4], wsu[4];
#pragma unroll
  for (int i = 0; i < 4; ++i) sxf[i] = Xs[qbase + i * 4];
#pragma unroll
  for (int jj = 0; jj < 4; ++jj) {
    wsg[jj] = WsG[n0 + wc + jj * 16 + l16];
    wsu[jj] = WsG[8192 + n0 + wc + jj * 16 + l16];
  }

  float av[4][4][4];   // [i][jj][r]
#pragma unroll
  for (int i = 0; i < 4; ++i)
#pragma unroll
    for (int jj = 0; jj < 4; ++jj) {
      float pg = sxf[i] * wsg[jj];
      float pu = sxf[i] * wsu[jj];
#pragma unroll
      for (int r = 0; r < 4; ++r) {
        float gv = (float)accg[i][jj][r] * pg;
        float uv = (float)accu[i][jj][r] * pu;
        av[i][jj][r] = (gv / (1.f + __expf(-gv))) * uv;
      }
    }

#pragma unroll
  for (int i = 0; i < 4; ++i)
#pragma unroll
    for (int r = 0; r < 4; ++r) {
      float m = 0.f;
#pragma unroll
      for (int jj = 0; jj < 4; ++jj) m = fmaxf(m, fabsf(av[i][jj][r]));
      m = fmaxf(m, __shfl_xor(m, 1));
      m = fmaxf(m, __shfl_xor(m, 2));
      m = fmaxf(m, __shfl_xor(m, 4));
      m = fmaxf(m, __shfl_xor(m, 8));
      if (l16 == 0) rmax[wcI][wr + i * 16 + quad * 4 + r] = m;
    }
  __syncthreads();
  if (tid < 32) {
    float m = 0.f;
#pragma unroll
    for (int k = 0; k < 4; ++k)
      m = fmaxf(m, fmaxf(rmax[0][tid * 4 + k], rmax[1][tid * 4 + k]));
    rmax4[tid] = m;
    As4[(n0 >> 7) * 1024 + (m0 >> 2) + tid] = m * (1.f / 127.f);
  }
  __syncthreads();

#pragma unroll
  for (int i = 0; i < 4; ++i) {
    float mx = rmax4[(wr >> 2) + i * 4 + quad];
    float inv = mx > 0.f ? 127.f / mx : 0.f;
#pragma unroll
    for (int r = 0; r < 4; ++r) {
      int mrow = wr + i * 16 + quad * 4 + r;
#pragma unroll
      for (int jj = 0; jj < 4; ++jj) {
        int q = (int)rintf(av[i][jj][r] * inv);
        lA[mrow * 128 + wc + jj * 16 + l16] = (signed char)q;
      }
    }
  }
  __syncthreads();

#pragma unroll
  for (int t = 0; t < 4; ++t) {
    int c = tid + 256 * t;
    int row = c >> 3;
    int col = (c & 7) * 16;
    *(int4*)(act + (size_t)(m0 + row) * 8192 + n0 + col) = *(const int4*)(lA + row * 128 + col);
  }
}

// ---------------- GEMM2: out = dequant(act)@Wd^T + bias (per-group rescale, exact) ----------------
__global__ __launch_bounds__(256, 4) void gemm_down_i8(
    const signed char* __restrict__ Aq, const signed char* __restrict__ Wq,
    const float* __restrict__ As4,   // [64][1024]
    const float* __restrict__ DsT,   // [64][3072]
    const float* __restrict__ bias,
    float* __restrict__ out) {
  const int K = 8192;
  const int bid = blockIdx.x;
  const int xcd = bid & 7;
  const int jb  = bid >> 3;
  const int jn  = jb % 12;
  const int jm  = jb / 12;
  const int n0  = (12 * (xcd & 1) + jn) * 128;
  const int m0  = (8 * (xcd >> 1) + jm) * 128;
  __shared__ signed char lA[16384];
  __shared__ signed char lB[16384];

  const int tid  = threadIdx.x;
  const int l    = tid & 63;
  const int quad = l >> 4;
  const int l16  = l & 15;
  const int wr   = ((tid >> 6) >> 1) * 64;
  const int wc   = ((tid >> 6) & 1) * 64;

  f32x2 fc[4][4][2] = {};

  int off[4];
#pragma unroll
  for (int jj = 0; jj < 4; ++jj) {
    int c   = tid + 256 * jj;
    int row = c >> 3;
    int log = (c & 7) ^ (row & 7);
    off[jj] = row * K + log * 16;
  }
  const signed char* baseA = Aq + (size_t)m0 * K;
  const signed char* baseB = Wq + (size_t)n0 * K;

  int aoff[2][4], boff[2][4];
#pragma unroll
  for (int h = 0; h < 2; ++h) {
    int slot = h * 4 + quad;
#pragma unroll
    for (int i = 0; i < 4; ++i) {
      int ra = wr + i * 16 + l16;
      aoff[h][i] = ra * 128 + ((slot ^ (ra & 7)) * 16);
      int rb = wc + i * 16 + l16;
      boff[h][i] = rb * 128 + ((slot ^ (rb & 7)) * 16);
    }
  }
  const int qbase = (m0 >> 2) + (wr >> 2) + quad;

  for (int g = 0; g < 64; ++g) {
    const int kk = g << 7;
#pragma unroll
    for (int jj = 0; jj < 4; ++jj) {
      gload16(baseA + off[jj] + kk, lA + (tid + 256 * jj) * 16);
      gload16(baseB + off[jj] + kk, lB + (tid + 256 * jj) * 16);
    }
    float sxq[4], sn[4];
#pragma unroll
    for (int i = 0; i < 4; ++i) sxq[i] = As4[g * 1024 + qbase + i * 4];
#pragma unroll
    for (int jj = 0; jj < 4; ++jj)
      sn[jj] = DsT[g * 3072 + n0 + wc + jj * 16 + l16];
    __syncthreads();

    i32x4 a[4][2];
#pragma unroll
    for (int i = 0; i < 4; ++i) {
      a[i][0] = *(const i32x4*)(lA + aoff[0][i]);
      a[i][1] = *(const i32x4*)(lA + aoff[1][i]);
    }
    __builtin_amdgcn_s_setprio(1);
#pragma unroll
    for (int jj = 0; jj < 4; ++jj) {
      i32x4 b0 = *(const i32x4*)(lB + boff[0][jj]);
      i32x4 b1 = *(const i32x4*)(lB + boff[1][jj]);
#pragma unroll
      for (int i = 0; i < 4; ++i) {
        i32x4 zero = {0, 0, 0, 0};
        i32x4 ic = __builtin_amdgcn_mfma_i32_16x16x64_i8(a[i][0], b0, zero, 0, 0, 0);
        ic = __builtin_amdgcn_mfma_i32_16x16x64_i8(a[i][1], b1, ic, 0, 0, 0);
        float ps = sxq[i] * sn[jj];
        f32x2 p2 = {ps, ps};
        f32x2 c01 = {(float)ic[0], (float)ic[1]};
        f32x2 c23 = {(float)ic[2], (float)ic[3]};
        fc[i][jj][0] = __builtin_elementwise_fma(c01, p2, fc[i][jj][0]);
        fc[i][jj][1] = __builtin_elementwise_fma(c23, p2, fc[i][jj][1]);
      }
    }
    __builtin_amdgcn_s_setprio(0);
    __syncthreads();
  }

  float bj[4];
#pragma unroll
  for (int jj = 0; jj < 4; ++jj) bj[jj] = bias[n0 + wc + jj * 16 + l16];

#pragma unroll
  for (int i = 0; i < 4; ++i)
#pragma unroll
    for (int jj = 0; jj < 4; ++jj)
#pragma unroll
      for (int r = 0; r < 4; ++r) {
        int m = m0 + wr + i * 16 + quad * 4 + r;
        int n = n0 + wc + jj * 16 + l16;
        out[(size_t)m * 3072 + n] = fc[i][jj][r >> 1][r & 1] + bj[jj];
      }
}

extern "C" void kernel_launch(void* const* d_in, const int* in_sizes, int n_in,
                              void* d_out, int out_size, void* d_ws, size_t ws_size,
                              hipStream_t stream) {
  const float* x        = (const float*)d_in[0];
  const int*   gup_qw   = (const int*)d_in[1];
  const int*   gup_qz   = (const int*)d_in[2];
  const float* gup_sc   = (const float*)d_in[3];
  const int*   down_qw  = (const int*)d_in[4];
  const int*   down_qz  = (const int*)d_in[5];
  const float* down_sc  = (const float*)d_in[6];
  const float* down_b   = (const float*)d_in[7];
  float* out = (float*)d_out;

  char* ws = (char*)d_ws;
  signed char* Xq    = (signed char*)(ws);                 // 12,582,912
  signed char* Wgupq = (signed char*)(ws + 12582912);      // 50,331,648
  signed char* Wdnq  = (signed char*)(ws + 62914560);      // 25,165,824
  signed char* Actq  = (signed char*)(ws + 88080384);      // 33,554,432
  float* Xs  = (float*)(ws + 121634816);                   // 1024 f32
  float* WsG = (float*)(ws + 121638912);                   // 16384 f32
  float* DsT = (float*)(ws + 121704448);                   // 64x3072 f32
  float* As4 = (float*)(ws + 122490880);                   // 64x1024 f32

  quant_x_flat<<<1024, 256, 0, stream>>>(x, Xq, Xs);
  requant_gup_flat<<<4096, 256, 0, stream>>>(gup_qw, gup_qz, gup_sc, Wgupq, WsG);
  requant_k<8192><<<12288, 256, 0, stream>>>(down_qw, down_qz, Wdnq);
  transpose_sc<<<768, 256, 0, stream>>>(down_sc, DsT, 3072, 64);
  gemm_gateup_i8<<<2048, 256, 0, stream>>>(Xq, Wgupq, Xs, WsG, Actq, As4);
  gemm_down_i8<<<768, 256, 0, stream>>>(Actq, Wdnq, As4, DsT, down_b, out);
}

// Round 7
// 795.118 us; speedup vs baseline: 1.3847x; 1.3847x over previous
//
#include <hip/hip_runtime.h>

// Phi3 quantized MLP on MI355X (gfx950) — R12: revert R11 bounds + K-split gemm_down.
// R11 post-mortem (FAIL 1101 us): launch_bounds(256,3/4) + unified VGPR/AGPR file ->
// accumulators spilled to scratch (VGPR 116->84, WRITE_SIZE 33->460 MB). Occupancy
// steps exist only at VGPR 64/128/256 (no 3-wave step); int32 acc regs count against
// the cap. NEVER bound min-occupancy on MFMA kernels with big accumulator files.
// R12: all GEMMs back to proven (256,2) [R4 codegen, 743 us]. gateup is ~88% of the
// 16x16 i8 ubench ceiling (209 us floor) — near done. gemm_down (<233 us, floor 104)
// has a structural tail: 768 blocks = 1.5 rounds @2 blk/CU. Fix: K-split x2 ->
// 1536 blocks (exactly 3 rounds), halves interleaved, partials via device-scope
// f32 atomicAdd into a zero_out-cleared output (self-contained per graph replay).
// Per-half math bit-identical to R9; absmax stays ~17.0.

typedef float f32x4 __attribute__((ext_vector_type(4)));
typedef float f32x2 __attribute__((ext_vector_type(2)));
typedef int   i32x4 __attribute__((ext_vector_type(4)));

__device__ __forceinline__ void gload16(const void* g, void* l) {
  __builtin_amdgcn_global_load_lds(
      (const __attribute__((address_space(1))) void*)g,
      (__attribute__((address_space(3))) void*)l, 16, 0, 0);
}

// ---------------- zero out (atomic targets must start at 0 every replay) ----------------
__global__ __launch_bounds__(256) void zero_out(float4* __restrict__ out4) {
  out4[(size_t)blockIdx.x * 256 + threadIdx.x] = float4{0.f, 0.f, 0.f, 0.f};
}

// ---------------- quantize x: f32 -> int8, ONE scale per row-quad (4 rows x full K) ----------------
__global__ __launch_bounds__(256) void quant_x_flat(const float* __restrict__ x,
                                                    signed char* __restrict__ Xq,
                                                    float* __restrict__ Xs) {
  int rq   = blockIdx.x;
  int w    = threadIdx.x >> 6;
  int lane = threadIdx.x & 63;
  size_t rowbase = ((size_t)rq * 4 + w) * 3072;
  __shared__ float wmax[4];
  float4 v[12];
  float m = 0.f;
#pragma unroll
  for (int it = 0; it < 12; ++it) {
    v[it] = *(const float4*)(x + rowbase + (lane + it * 64) * 4);
    m = fmaxf(m, fmaxf(fmaxf(fabsf(v[it].x), fabsf(v[it].y)),
                       fmaxf(fabsf(v[it].z), fabsf(v[it].w))));
  }
#pragma unroll
  for (int s = 1; s < 64; s <<= 1) m = fmaxf(m, __shfl_xor(m, s));
  if (lane == 0) wmax[w] = m;
  __syncthreads();
  float m4 = fmaxf(fmaxf(wmax[0], wmax[1]), fmaxf(wmax[2], wmax[3]));
  float inv = m4 > 0.f ? 127.f / m4 : 0.f;
#pragma unroll
  for (int it = 0; it < 12; ++it) {
    int a = (int)rintf(v[it].x * inv);
    int b = (int)rintf(v[it].y * inv);
    int c = (int)rintf(v[it].z * inv);
    int d = (int)rintf(v[it].w * inv);
    int pk = (a & 0xff) | ((b & 0xff) << 8) | ((c & 0xff) << 16) | ((d & 0xff) << 24);
    *(int*)(Xq + rowbase + (lane + it * 64) * 4) = pk;
  }
  if (threadIdx.x == 0) Xs[rq] = m4 * (1.f / 127.f);
}

// ---------------- requant gate/up weights: per-ROW flat int8 + row scale ----------------
__global__ __launch_bounds__(256) void requant_gup_flat(const int* __restrict__ qw,
                                                        const int* __restrict__ qz,
                                                        const float* __restrict__ sc,
                                                        signed char* __restrict__ W,
                                                        float* __restrict__ Ws) {
  int w    = threadIdx.x >> 6;
  int lane = threadIdx.x & 63;
  int r    = blockIdx.x * 4 + w;
  float smax = (lane < 24) ? sc[r * 24 + lane] : 0.f;
#pragma unroll
  for (int s = 1; s < 64; s <<= 1) smax = fmaxf(smax, __shfl_xor(smax, s));
  float rs    = smax * (15.f / 127.f);
  float invrs = 127.f / (15.f * smax);
#pragma unroll
  for (int it = 0; it < 12; ++it) {
    int cidx = lane + it * 64;
    int g    = cidx >> 5;
    int z    = qz[r * 24 + g];
    float f  = sc[r * 24 + g] * invrs;
    int4 q   = *(const int4*)(qw + (size_t)r * 3072 + cidx * 4);
    int a = (int)rintf((float)(q.x - z) * f);
    int b = (int)rintf((float)(q.y - z) * f);
    int c = (int)rintf((float)(q.z - z) * f);
    int d = (int)rintf((float)(q.w - z) * f);
    int pk = (a & 0xff) | ((b & 0xff) << 8) | ((c & 0xff) << 16) | ((d & 0xff) << 24);
    *(int*)(W + (size_t)r * 3072 + cidx * 4) = pk;
  }
  if (lane == 0) Ws[r] = rs;
}

// ---------------- requant down weights: int32 q,z -> int8 (q - z), exact ----------------
template <int K>
__global__ __launch_bounds__(256) void requant_k(const int* __restrict__ qw,
                                                 const int* __restrict__ qz,
                                                 signed char* __restrict__ W) {
  constexpr int KG = K / 128;
  constexpr int perrow = K / 8;
  int idx = blockIdx.x * 256 + threadIdx.x;
  int row = idx / perrow;
  int c8  = idx - row * perrow;
  int k   = c8 << 3;
  int z   = qz[row * KG + (k >> 7)];
  const int4* q4 = (const int4*)(qw + (size_t)row * K + k);
  int4 qa = q4[0];
  int4 qb = q4[1];
  int b0 = ((qa.x - z) & 0xff) | (((qa.y - z) & 0xff) << 8) |
           (((qa.z - z) & 0xff) << 16) | (((qa.w - z) & 0xff) << 24);
  int b1 = ((qb.x - z) & 0xff) | (((qb.y - z) & 0xff) << 8) |
           (((qb.z - z) & 0xff) << 16) | (((qb.w - z) & 0xff) << 24);
  int2 o; o.x = b0; o.y = b1;
  *(int2*)(W + (size_t)row * K + k) = o;
}

// ---------------- scale transpose: [R][G] -> [G][R] ----------------
__global__ __launch_bounds__(256) void transpose_sc(const float* __restrict__ in,
                                                    float* __restrict__ out,
                                                    int R, int G) {
  int idx = blockIdx.x * 256 + threadIdx.x;
  int r = idx / G;
  int g = idx - r * G;
  out[(size_t)g * R + r] = in[idx];
}

// LDS tile: 128 rows x 128 bytes, XOR-swizzled (phys chunk p holds logical p^(row&7)).

// ---------------- GEMM1: act = silu(x@Wg^T)*(x@Wu^T), flat int8, pure int32 K-loop ----------------
__global__ __launch_bounds__(256, 2) void gemm_gateup_i8(
    const signed char* __restrict__ Xq, const signed char* __restrict__ Wq,
    const float* __restrict__ Xs,    // [1024] per-row-quad x scale
    const float* __restrict__ WsG,   // [16384] per-row weight scale (gate then up)
    signed char* __restrict__ act,   // [4096][8192]
    float* __restrict__ As4) {       // [64][1024]
  const int K = 3072;
  const int bid = blockIdx.x;
  const int xcd = bid & 7;
  const int jb  = bid >> 3;
  const int n0  = ((xcd << 3) + (jb & 7)) * 128;
  const int m0  = (jb >> 3) * 128;
  __shared__ signed char lA[16384];
  __shared__ signed char lG[16384];
  __shared__ signed char lU[16384];
  __shared__ float rmax[2][128];
  __shared__ float rmax4[32];

  const int tid  = threadIdx.x;
  const int l    = tid & 63;
  const int quad = l >> 4;
  const int l16  = l & 15;
  const int wcI  = (tid >> 6) & 1;
  const int wr   = ((tid >> 6) >> 1) * 64;
  const int wc   = wcI * 64;

  i32x4 accg[4][4] = {};
  i32x4 accu[4][4] = {};

  int off[4];
#pragma unroll
  for (int jj = 0; jj < 4; ++jj) {
    int c   = tid + 256 * jj;
    int row = c >> 3;
    int log = (c & 7) ^ (row & 7);
    off[jj] = row * K + log * 16;
  }
  const signed char* baseA = Xq + (size_t)m0 * K;
  const signed char* baseG = Wq + (size_t)n0 * K;
  const signed char* baseU = Wq + (size_t)(8192 + n0) * K;

  int aoff[2][4], boff[2][4];
#pragma unroll
  for (int h = 0; h < 2; ++h) {
    int slot = h * 4 + quad;
#pragma unroll
    for (int i = 0; i < 4; ++i) {
      int ra = wr + i * 16 + l16;
      aoff[h][i] = ra * 128 + ((slot ^ (ra & 7)) * 16);
      int rb = wc + i * 16 + l16;
      boff[h][i] = rb * 128 + ((slot ^ (rb & 7)) * 16);
    }
  }
  const int qbase = (m0 >> 2) + (wr >> 2) + quad;

  for (int g = 0; g < 24; ++g) {
    const int kk = g << 7;
#pragma unroll
    for (int jj = 0; jj < 4; ++jj) {
      gload16(baseA + off[jj] + kk, lA + (tid + 256 * jj) * 16);
      gload16(baseG + off[jj] + kk, lG + (tid + 256 * jj) * 16);
      gload16(baseU + off[jj] + kk, lU + (tid + 256 * jj) * 16);
    }
    __syncthreads();

    i32x4 a[4][2];
#pragma unroll
    for (int i = 0; i < 4; ++i) {
      a[i][0] = *(const i32x4*)(lA + aoff[0][i]);
      a[i][1] = *(const i32x4*)(lA + aoff[1][i]);
    }
    __builtin_amdgcn_s_setprio(1);
#pragma unroll
    for (int jj = 0; jj < 4; ++jj) {
      i32x4 bg0 = *(const i32x4*)(lG + boff[0][jj]);
      i32x4 bg1 = *(const i32x4*)(lG + boff[1][jj]);
      i32x4 bu0 = *(const i32x4*)(lU + boff[0][jj]);
      i32x4 bu1 = *(const i32x4*)(lU + boff[1][jj]);
#pragma unroll
      for (int i = 0; i < 4; ++i) {
        accg[i][jj] = __builtin_amdgcn_mfma_i32_16x16x64_i8(a[i][0], bg0, accg[i][jj], 0, 0, 0);
        accg[i][jj] = __builtin_amdgcn_mfma_i32_16x16x64_i8(a[i][1], bg1, accg[i][jj], 0, 0, 0);
        accu[i][jj] = __builtin_amdgcn_mfma_i32_16x16x64_i8(a[i][0], bu0, accu[i][jj], 0, 0, 0);
        accu[i][jj] = __builtin_amdgcn_mfma_i32_16x16x64_i8(a[i][1], bu1, accu[i][jj], 0, 0, 0);
      }
    }
    __builtin_amdgcn_s_setprio(0);
    __syncthreads();
  }

  // ---- epilogue: dequant (flat scales) -> silu(g)*u -> quad-shared absmax -> int8 ----
  float sxf[4], wsg[4], wsu[4];
#pragma unroll
  for (int i = 0; i < 4; ++i) sxf[i] = Xs[qbase + i * 4];
#pragma unroll
  for (int jj = 0; jj < 4; ++jj) {
    wsg[jj] = WsG[n0 + wc + jj * 16 + l16];
    wsu[jj] = WsG[8192 + n0 + wc + jj * 16 + l16];
  }

  float av[4][4][4];   // [i][jj][r]
#pragma unroll
  for (int i = 0; i < 4; ++i)
#pragma unroll
    for (int jj = 0; jj < 4; ++jj) {
      float pg = sxf[i] * wsg[jj];
      float pu = sxf[i] * wsu[jj];
#pragma unroll
      for (int r = 0; r < 4; ++r) {
        float gv = (float)accg[i][jj][r] * pg;
        float uv = (float)accu[i][jj][r] * pu;
        av[i][jj][r] = (gv / (1.f + __expf(-gv))) * uv;
      }
    }

#pragma unroll
  for (int i = 0; i < 4; ++i)
#pragma unroll
    for (int r = 0; r < 4; ++r) {
      float m = 0.f;
#pragma unroll
      for (int jj = 0; jj < 4; ++jj) m = fmaxf(m, fabsf(av[i][jj][r]));
      m = fmaxf(m, __shfl_xor(m, 1));
      m = fmaxf(m, __shfl_xor(m, 2));
      m = fmaxf(m, __shfl_xor(m, 4));
      m = fmaxf(m, __shfl_xor(m, 8));
      if (l16 == 0) rmax[wcI][wr + i * 16 + quad * 4 + r] = m;
    }
  __syncthreads();
  if (tid < 32) {
    float m = 0.f;
#pragma unroll
    for (int k = 0; k < 4; ++k)
      m = fmaxf(m, fmaxf(rmax[0][tid * 4 + k], rmax[1][tid * 4 + k]));
    rmax4[tid] = m;
    As4[(n0 >> 7) * 1024 + (m0 >> 2) + tid] = m * (1.f / 127.f);
  }
  __syncthreads();

#pragma unroll
  for (int i = 0; i < 4; ++i) {
    float mx = rmax4[(wr >> 2) + i * 4 + quad];
    float inv = mx > 0.f ? 127.f / mx : 0.f;
#pragma unroll
    for (int r = 0; r < 4; ++r) {
      int mrow = wr + i * 16 + quad * 4 + r;
#pragma unroll
      for (int jj = 0; jj < 4; ++jj) {
        int q = (int)rintf(av[i][jj][r] * inv);
        lA[mrow * 128 + wc + jj * 16 + l16] = (signed char)q;
      }
    }
  }
  __syncthreads();

#pragma unroll
  for (int t = 0; t < 4; ++t) {
    int c = tid + 256 * t;
    int row = c >> 3;
    int col = (c & 7) * 16;
    *(int4*)(act + (size_t)(m0 + row) * 8192 + n0 + col) = *(const int4*)(lA + row * 128 + col);
  }
}

// ---------------- GEMM2: out += dequant(act)@Wd^T (+bias), K-split x2, atomic combine ----------------
__global__ __launch_bounds__(256, 2) void gemm_down_i8(
    const signed char* __restrict__ Aq, const signed char* __restrict__ Wq,
    const float* __restrict__ As4,   // [64][1024]
    const float* __restrict__ DsT,   // [64][3072]
    const float* __restrict__ bias,
    float* __restrict__ out) {
  const int K = 8192;
  const int bid  = blockIdx.x;
  const int xcd  = bid & 7;
  const int jb2  = bid >> 3;        // 0..191
  const int half = jb2 & 1;         // interleaved halves -> no scheduling tail
  const int jb   = jb2 >> 1;        // 0..95
  const int jn   = jb % 12;
  const int jm   = jb / 12;
  const int n0   = (12 * (xcd & 1) + jn) * 128;
  const int m0   = (8 * (xcd >> 1) + jm) * 128;
  __shared__ signed char lA[16384];
  __shared__ signed char lB[16384];

  const int tid  = threadIdx.x;
  const int l    = tid & 63;
  const int quad = l >> 4;
  const int l16  = l & 15;
  const int wr   = ((tid >> 6) >> 1) * 64;
  const int wc   = ((tid >> 6) & 1) * 64;

  f32x2 fc[4][4][2] = {};

  int off[4];
#pragma unroll
  for (int jj = 0; jj < 4; ++jj) {
    int c   = tid + 256 * jj;
    int row = c >> 3;
    int log = (c & 7) ^ (row & 7);
    off[jj] = row * K + log * 16;
  }
  const signed char* baseA = Aq + (size_t)m0 * K;
  const signed char* baseB = Wq + (size_t)n0 * K;

  int aoff[2][4], boff[2][4];
#pragma unroll
  for (int h = 0; h < 2; ++h) {
    int slot = h * 4 + quad;
#pragma unroll
    for (int i = 0; i < 4; ++i) {
      int ra = wr + i * 16 + l16;
      aoff[h][i] = ra * 128 + ((slot ^ (ra & 7)) * 16);
      int rb = wc + i * 16 + l16;
      boff[h][i] = rb * 128 + ((slot ^ (rb & 7)) * 16);
    }
  }
  const int qbase = (m0 >> 2) + (wr >> 2) + quad;

  const int g0 = half * 32;
  for (int g = g0; g < g0 + 32; ++g) {
    const int kk = g << 7;
#pragma unroll
    for (int jj = 0; jj < 4; ++jj) {
      gload16(baseA + off[jj] + kk, lA + (tid + 256 * jj) * 16);
      gload16(baseB + off[jj] + kk, lB + (tid + 256 * jj) * 16);
    }
    float sxq[4], sn[4];
#pragma unroll
    for (int i = 0; i < 4; ++i) sxq[i] = As4[g * 1024 + qbase + i * 4];
#pragma unroll
    for (int jj = 0; jj < 4; ++jj)
      sn[jj] = DsT[g * 3072 + n0 + wc + jj * 16 + l16];
    __syncthreads();

    i32x4 a[4][2];
#pragma unroll
    for (int i = 0; i < 4; ++i) {
      a[i][0] = *(const i32x4*)(lA + aoff[0][i]);
      a[i][1] = *(const i32x4*)(lA + aoff[1][i]);
    }
    __builtin_amdgcn_s_setprio(1);
#pragma unroll
    for (int jj = 0; jj < 4; ++jj) {
      i32x4 b0 = *(const i32x4*)(lB + boff[0][jj]);
      i32x4 b1 = *(const i32x4*)(lB + boff[1][jj]);
#pragma unroll
      for (int i = 0; i < 4; ++i) {
        i32x4 zero = {0, 0, 0, 0};
        i32x4 ic = __builtin_amdgcn_mfma_i32_16x16x64_i8(a[i][0], b0, zero, 0, 0, 0);
        ic = __builtin_amdgcn_mfma_i32_16x16x64_i8(a[i][1], b1, ic, 0, 0, 0);
        float ps = sxq[i] * sn[jj];
        f32x2 p2 = {ps, ps};
        f32x2 c01 = {(float)ic[0], (float)ic[1]};
        f32x2 c23 = {(float)ic[2], (float)ic[3]};
        fc[i][jj][0] = __builtin_elementwise_fma(c01, p2, fc[i][jj][0]);
        fc[i][jj][1] = __builtin_elementwise_fma(c23, p2, fc[i][jj][1]);
      }
    }
    __builtin_amdgcn_s_setprio(0);
    __syncthreads();
  }

  float bj[4];
#pragma unroll
  for (int jj = 0; jj < 4; ++jj) bj[jj] = (half == 0) ? bias[n0 + wc + jj * 16 + l16] : 0.f;

#pragma unroll
  for (int i = 0; i < 4; ++i)
#pragma unroll
    for (int jj = 0; jj < 4; ++jj)
#pragma unroll
      for (int r = 0; r < 4; ++r) {
        int m = m0 + wr + i * 16 + quad * 4 + r;
        int n = n0 + wc + jj * 16 + l16;
        atomicAdd(&out[(size_t)m * 3072 + n], fc[i][jj][r >> 1][r & 1] + bj[jj]);
      }
}

extern "C" void kernel_launch(void* const* d_in, const int* in_sizes, int n_in,
                              void* d_out, int out_size, void* d_ws, size_t ws_size,
                              hipStream_t stream) {
  const float* x        = (const float*)d_in[0];
  const int*   gup_qw   = (const int*)d_in[1];
  const int*   gup_qz   = (const int*)d_in[2];
  const float* gup_sc   = (const float*)d_in[3];
  const int*   down_qw  = (const int*)d_in[4];
  const int*   down_qz  = (const int*)d_in[5];
  const float* down_sc  = (const float*)d_in[6];
  const float* down_b   = (const float*)d_in[7];
  float* out = (float*)d_out;

  char* ws = (char*)d_ws;
  signed char* Xq    = (signed char*)(ws);                 // 12,582,912
  signed char* Wgupq = (signed char*)(ws + 12582912);      // 50,331,648
  signed char* Wdnq  = (signed char*)(ws + 62914560);      // 25,165,824
  signed char* Actq  = (signed char*)(ws + 88080384);      // 33,554,432
  float* Xs  = (float*)(ws + 121634816);                   // 1024 f32
  float* WsG = (float*)(ws + 121638912);                   // 16384 f32
  float* DsT = (float*)(ws + 121704448);                   // 64x3072 f32
  float* As4 = (float*)(ws + 122490880);                   // 64x1024 f32

  zero_out<<<12288, 256, 0, stream>>>((float4*)out);
  quant_x_flat<<<1024, 256, 0, stream>>>(x, Xq, Xs);
  requant_gup_flat<<<4096, 256, 0, stream>>>(gup_qw, gup_qz, gup_sc, Wgupq, WsG);
  requant_k<8192><<<12288, 256, 0, stream>>>(down_qw, down_qz, Wdnq);
  transpose_sc<<<768, 256, 0, stream>>>(down_sc, DsT, 3072, 64);
  gemm_gateup_i8<<<2048, 256, 0, stream>>>(Xq, Wgupq, Xs, WsG, Actq, As4);
  gemm_down_i8<<<1536, 256, 0, stream>>>(Actq, Wdnq, As4, DsT, down_b, out);
}